// Round 11
// baseline (105.767 us; speedup 1.0000x reference)
//
#include <hip/hip_runtime.h>
#include <hip/hip_bf16.h>

#define B_ 2
#define T_ 2048
#define C_ 1024
#define NH_ 16
#define NKV_ 4
#define HD_ 64
#define NQKV_ 1536           // (NH + 2*NKV) * HD
#define M_ 4096              // B_ * T_

typedef __attribute__((ext_vector_type(8))) __bf16 bf16x8;
typedef __attribute__((ext_vector_type(4))) __bf16 bf16x4;
typedef __attribute__((ext_vector_type(2))) __bf16 bf16x2;
typedef __attribute__((ext_vector_type(4))) float f32x4;
typedef __attribute__((ext_vector_type(4))) unsigned int u32x4;

// raw v_exp_f32 (D = 2^S0): 1 instruction, ~1 ulp — plenty for bf16 outputs.
__device__ __forceinline__ float fast_exp2(float x) { return __builtin_amdgcn_exp2f(x); }

#define GLOAD_LDS16(gptr, lptr)                                                        \
  __builtin_amdgcn_global_load_lds(                                                    \
      (const __attribute__((address_space(1))) unsigned int*)(gptr),                   \
      (__attribute__((address_space(3))) unsigned int*)(lptr), 16, 0, 0)

// ---------------- cast x (fp32 -> bf16), 4 elems/thread ----------------
__global__ __launch_bounds__(256) void cast_x_kernel(const float* __restrict__ in,
                                                     __bf16* __restrict__ out) {
  const int i = blockIdx.x * 256 + threadIdx.x;
  const float4 v = ((const float4*)in)[i];
  bf16x4 o;
  o.x = (__bf16)v.x; o.y = (__bf16)v.y; o.z = (__bf16)v.z; o.w = (__bf16)v.w;
  ((bf16x4*)out)[i] = o;
}

// ---------- transpose + cast: in [K][N] fp32 -> out [N][K] bf16 ----------
__global__ __launch_bounds__(256) void transpose_cast_kernel(const float* __restrict__ in,
                                                             __bf16* __restrict__ out,
                                                             int K, int N) {
  __shared__ __bf16 tile[64][72];  // [n_local][k_local], padded
  const int n0 = blockIdx.x * 64, k0 = blockIdx.y * 64;
  const int tid = threadIdx.x;
  const int tr = tid >> 4, tc4 = (tid & 15) << 2;
  #pragma unroll
  for (int p = 0; p < 4; ++p) {
    const int k = k0 + p * 16 + tr;
    const float4 v = *(const float4*)&in[(size_t)k * N + n0 + tc4];
    tile[tc4 + 0][p * 16 + tr] = (__bf16)v.x;
    tile[tc4 + 1][p * 16 + tr] = (__bf16)v.y;
    tile[tc4 + 2][p * 16 + tr] = (__bf16)v.z;
    tile[tc4 + 3][p * 16 + tr] = (__bf16)v.w;
  }
  __syncthreads();
  #pragma unroll
  for (int p = 0; p < 4; ++p) {
    const int n = n0 + p * 16 + tr;
    bf16x4 o;
    o.x = tile[p * 16 + tr][tc4 + 0];
    o.y = tile[p * 16 + tr][tc4 + 1];
    o.z = tile[p * 16 + tr][tc4 + 2];
    o.w = tile[p * 16 + tr][tc4 + 3];
    *(bf16x4*)&out[(size_t)n * K + k0 + tc4] = o;
  }
}

// ---------------- RoPE cos/sin tables [T][32] fp32 ----------------
__global__ __launch_bounds__(256) void rope_table_kernel(float* __restrict__ cosT,
                                                         float* __restrict__ sinT) {
  const int idx = blockIdx.x * 256 + threadIdx.x;  // T*32 total
  const int t = idx >> 5, i = idx & 31;
  const float inv = powf(10000.0f, -(float)i * (1.0f / 32.0f));
  const float ang = (float)t * inv;
  cosT[idx] = cosf(ang);
  sinT[idx] = sinf(ang);
}

// ------- bf16 TN GEMM: A[M][K] * Bt[N][K]^T -> C[M][N] (OutT) -------
// 128x64 tile, BK=64, 4 waves (2x2, each 64x32 out). Double-buffered
// global_load_lds (w=16): stage(t+1) issues BEFORE compute(t); vmcnt(0)+
// barrier once per tile. Pre-swizzled SOURCE + linear LDS dest (rule 21).
template <typename OutT>
__global__ __launch_bounds__(256) void gemm_tn_kernel(const __bf16* __restrict__ A,
                                                      const __bf16* __restrict__ Bt,
                                                      OutT* __restrict__ C, int N, int K) {
  __shared__ __align__(16) __bf16 lA[2][128 * 64];
  __shared__ __align__(16) __bf16 lB[2][64 * 64];
  const int tid = threadIdx.x;
  const int lane = tid & 63;
  const int wave = tid >> 6;
  const int wr = wave >> 1, wc = wave & 1;
  const int m0 = blockIdx.y * 128, n0 = blockIdx.x * 64;
  const int srow = tid >> 3, kc = tid & 7;  // staging: 8 threads/row, 16B chunks
  const int r16 = lane & 15, g = lane >> 4;
  f32x4 acc[4][2] = {};
  const int nt = K >> 6;

#define GSTAGE(buf, k0)                                                                   \
  {                                                                                       \
    _Pragma("unroll")                                                                     \
    for (int p = 0; p < 4; ++p) {                                                         \
      const int row = p * 32 + srow;                                                      \
      const int sw = (kc ^ (row & 7)) * 8;                                                \
      GLOAD_LDS16(&A[(size_t)(m0 + row) * K + (k0) + sw], &lA[buf][row * 64 + kc * 8]);   \
    }                                                                                     \
    _Pragma("unroll")                                                                     \
    for (int p = 0; p < 2; ++p) {                                                         \
      const int row = p * 32 + srow;                                                      \
      const int sw = (kc ^ (row & 7)) * 8;                                                \
      GLOAD_LDS16(&Bt[(size_t)(n0 + row) * K + (k0) + sw], &lB[buf][row * 64 + kc * 8]);  \
    }                                                                                     \
  }

  GSTAGE(0, 0);
  asm volatile("s_waitcnt vmcnt(0)" ::: "memory");
  __syncthreads();
  int cur = 0;
  for (int t = 0; t < nt; ++t) {
    if (t + 1 < nt) GSTAGE(cur ^ 1, (t + 1) << 6);   // loads fly under compute
    #pragma unroll
    for (int ks = 0; ks < 64; ks += 32) {
      bf16x8 af[4], bfr[2];
      const int kch = (ks >> 3) + g;
      #pragma unroll
      for (int mi = 0; mi < 4; ++mi) {
        const int row = wr * 64 + mi * 16 + r16;
        af[mi] = *(const bf16x8*)&lA[cur][row * 64 + (kch ^ (row & 7)) * 8];
      }
      #pragma unroll
      for (int ni = 0; ni < 2; ++ni) {
        const int row = wc * 32 + ni * 16 + r16;
        bfr[ni] = *(const bf16x8*)&lB[cur][row * 64 + (kch ^ (row & 7)) * 8];
      }
      #pragma unroll
      for (int mi = 0; mi < 4; ++mi)
        #pragma unroll
        for (int ni = 0; ni < 2; ++ni)
          acc[mi][ni] = __builtin_amdgcn_mfma_f32_16x16x32_bf16(af[mi], bfr[ni], acc[mi][ni], 0, 0, 0);
    }
    asm volatile("s_waitcnt vmcnt(0)" ::: "memory");  // next-tile loads landed
    __syncthreads();
    cur ^= 1;
  }
  // epilogue: D layout col=lane&15, row=(lane>>4)*4+j
  #pragma unroll
  for (int mi = 0; mi < 4; ++mi) {
    const int r0 = m0 + wr * 64 + mi * 16 + g * 4;
    #pragma unroll
    for (int ni = 0; ni < 2; ++ni) {
      const int c = n0 + wc * 32 + ni * 16 + r16;
      #pragma unroll
      for (int j = 0; j < 4; ++j)
        C[(size_t)(r0 + j) * N + c] = (OutT)acc[mi][ni][j];
    }
  }
#undef GSTAGE
}

// ---- RoPE on q,k (bf16 qkv) -> Q[b][h][t][d], K[b][kvh][t][d] bf16 ----
// 8 elems (4 rotation pairs) per thread: bf16x8 load, float4 cos/sin, one
// 16B store (G13). Q additionally pre-scaled by 1/8*log2(e).
__global__ __launch_bounds__(256) void rope_qk_kernel(const __bf16* __restrict__ qkv,
                                                      const float* __restrict__ cosT,
                                                      const float* __restrict__ sinT,
                                                      __bf16* __restrict__ Q,
                                                      __bf16* __restrict__ Kb) {
  const int idx = blockIdx.x * 256 + threadIdx.x;  // M_*(NH+NKV)*8 total
  const int i8 = idx & 7;
  const int rest = idx >> 3;
  const int head = rest % (NH_ + NKV_);
  const int row = rest / (NH_ + NKV_);
  const int b = row >> 11, t = row & 2047;
  const float4 cv = *(const float4*)&cosT[t * 32 + i8 * 4];
  const float4 sv = *(const float4*)&sinT[t * 32 + i8 * 4];
  const bf16x8 v = *(const bf16x8*)&qkv[(size_t)row * NQKV_ + head * HD_ + i8 * 8];
  const bool isq = head < NH_;
  const float qs = isq ? 0.125f * 1.44269504f : 1.0f;
  bf16x8 o;
  #pragma unroll
  for (int p = 0; p < 4; ++p) {
    const float x1 = (float)v[2 * p], x2 = (float)v[2 * p + 1];
    const float c = (&cv.x)[p], s = (&sv.x)[p];
    o[2 * p]     = (__bf16)((x1 * c - x2 * s) * qs);
    o[2 * p + 1] = (__bf16)((x1 * s + x2 * c) * qs);
  }
  __bf16* dst = isq ? &Q[(((size_t)b * NH_ + head) * T_ + t) * HD_ + i8 * 8]
                    : &Kb[(((size_t)b * NKV_ + (head - NH_)) * T_ + t) * HD_ + i8 * 8];
  *(bf16x8*)dst = o;
}

// ---- V transpose: bf16 qkv v-part -> Vt[b][kvh][d][t] bf16 (LDS tiled) ----
__global__ __launch_bounds__(256) void v_transpose_kernel(const __bf16* __restrict__ qkv,
                                                          __bf16* __restrict__ Vt) {
  __shared__ __bf16 tile[64][72];  // [d][t_local], padded
  const int blk = blockIdx.x;      // B*NKV*(T/64)
  const int t0 = (blk & 31) * 64;
  const int kvh = (blk >> 5) & 3;
  const int b = blk >> 7;
  const int tid = threadIdx.x;
  const int tr = tid >> 4, c4 = (tid & 15) << 2;
  #pragma unroll
  for (int p = 0; p < 4; ++p) {
    const int t = t0 + p * 16 + tr;
    const bf16x4 v = *(const bf16x4*)&qkv[(size_t)(b * T_ + t) * NQKV_ + (NH_ + NKV_) * HD_ + kvh * HD_ + c4];
    tile[c4 + 0][p * 16 + tr] = v.x;
    tile[c4 + 1][p * 16 + tr] = v.y;
    tile[c4 + 2][p * 16 + tr] = v.z;
    tile[c4 + 3][p * 16 + tr] = v.w;
  }
  __syncthreads();
  #pragma unroll
  for (int p = 0; p < 4; ++p) {
    const int d = p * 16 + tr;
    bf16x4 o;
    o.x = tile[d][c4 + 0]; o.y = tile[d][c4 + 1];
    o.z = tile[d][c4 + 2]; o.w = tile[d][c4 + 3];
    *(bf16x4*)&Vt[(((size_t)b * NKV_ + kvh) * HD_ + d) * T_ + t0 + c4] = o;
  }
}

// ---- flash attention, triangle-paired, swapped-QK softmax, K/V LDS dbuf ----
// Block pair index i handles q-tiles {i, 31-i} in one shared KV sweep (33
// tile-activations/block -> uniform). K/V double-buffered in LDS via
// global_load_lds; ONE barrier per tile. NEW: kf/vf fragments hoisted into
// registers ONCE per KV-tile and shared by both active sides (-44% LDS reads
// on merged tiles; attn is LDS-throughput-bound per R8's split-null датum).
// Per-side sequence (QK -> softmax -> fence -> PV) unchanged from R7.
__global__ __launch_bounds__(256) void attn_kernel(const __bf16* __restrict__ Q,
                                                   const __bf16* __restrict__ Kb,
                                                   const __bf16* __restrict__ Vt,
                                                   __bf16* __restrict__ Y) {
  __shared__ __align__(16) __bf16 lK[2][64 * 64];   // [kv][d], swizzled
  __shared__ __align__(16) __bf16 lV[2][64 * 64];   // [d][kv], swizzled
  __shared__ __align__(16) __bf16 pP[4][16 * 64];   // per-wave [q][kv], swizzled
  const int tid = threadIdx.x;
  const int lane = tid & 63, wave = tid >> 6;
  const int r16 = lane & 15, g = lane >> 4;
  // bijective XCD swizzle (T1): 512 blocks, 8 XCDs -> 64 contiguous logical
  // ids per XCD so blocks sharing (b,kvh)'s K/V co-locate in one L2.
  const int logical = (blockIdx.x & 7) * 64 + (blockIdx.x >> 3);
  const int i = logical & 15;        // pair index: q-tiles {i, 31-i}
  const int bh = logical >> 4;
  const int b = bh >> 4, h = bh & 15;
  const int kvh = h >> 2;  // GQA rep = 4
  const __bf16* Qp = Q + ((size_t)b * NH_ + h) * T_ * HD_;
  const __bf16* Kp = Kb + ((size_t)b * NKV_ + kvh) * T_ * HD_;
  const __bf16* Vp = Vt + ((size_t)b * NKV_ + kvh) * HD_ * T_;
  const int qtile[2] = { i, 31 - i };
  const int srow = tid >> 3, kc = tid & 7;          // staging: 8x16B chunks/row

#define ASTAGE(buf, kv0_)                                                                  \
  {                                                                                        \
    _Pragma("unroll")                                                                      \
    for (int p = 0; p < 2; ++p) {                                                          \
      const int row = p * 32 + srow;                                                       \
      const int sw = (kc ^ (row & 7)) * 8;                                                 \
      GLOAD_LDS16(&Kp[(size_t)((kv0_) + row) * HD_ + sw], &lK[buf][row * 64 + kc * 8]);    \
      GLOAD_LDS16(&Vp[(size_t)row * T_ + (kv0_) + sw], &lV[buf][row * 64 + kc * 8]);       \
    }                                                                                      \
  }

  // Q fragments; pre-scaled by 1/8*log2e in rope_qk. B-operand of swapped QK.
  bf16x8 qf[2][2];
  #pragma unroll
  for (int sd = 0; sd < 2; ++sd)
    #pragma unroll
    for (int c = 0; c < 2; ++c)
      qf[sd][c] = *(const bf16x8*)&Qp[(size_t)(qtile[sd] * 64 + wave * 16 + r16) * HD_ + (c * 4 + g) * 8];

  f32x4 o[2][4] = {};
  float mS[2], lS[2];
  #pragma unroll
  for (int sd = 0; sd < 2; ++sd) { mS[sd] = -__builtin_inff(); lS[sd] = 0.0f; }

  // softmax + P-write for one side (lane owns full row q=qw+r16 of S^T)
  auto sm_side = [&](f32x4 (&s)[4], int sd) {
    // in-lane 16->1 max, max3-shaped triples (T17)
    float t0 = fmaxf(fmaxf(s[0][0], s[0][1]), s[0][2]);
    float t1 = fmaxf(fmaxf(s[0][3], s[1][0]), s[1][1]);
    float t2 = fmaxf(fmaxf(s[1][2], s[1][3]), s[2][0]);
    float t3 = fmaxf(fmaxf(s[2][1], s[2][2]), s[2][3]);
    float t4 = fmaxf(fmaxf(s[3][0], s[3][1]), s[3][2]);
    float pm = fmaxf(fmaxf(t0, t1), t2);
    pm = fmaxf(pm, fmaxf(t3, t4));
    pm = fmaxf(pm, s[3][3]);
    pm = fmaxf(pm, __shfl_xor(pm, 16));
    pm = fmaxf(pm, __shfl_xor(pm, 32));
    const bool upd = pm > mS[sd] + 8.0f;   // deferred-max (T13)
    const float nm = upd ? pm : mS[sd];
    const float sc = fast_exp2(mS[sd] - nm);   // ==1.0 exactly when !upd
    mS[sd] = nm;
    lS[sd] *= sc;
    if (__any(upd)) {  // redistribute sc from q=r16 layout to (g,j) layout
      #pragma unroll
      for (int j = 0; j < 4; ++j) {
        const float scj = __shfl(sc, g * 4 + j);
        #pragma unroll
        for (int nf = 0; nf < 4; ++nf) o[sd][nf][j] *= scj;
      }
    }
    // P = exp2(S-m): write each pb chunk ASAP (hides DS latency under the
    // remaining exp2s and the rs shfl chain), reduce rs after.
    float rs = 0.0f;
    #pragma unroll
    for (int ni = 0; ni < 4; ++ni) {
      bf16x4 pb;
      #pragma unroll
      for (int j = 0; j < 4; ++j) {
        const float pv = fast_exp2(s[ni][j] - mS[sd]);
        rs += pv;
        pb[j] = (__bf16)pv;
      }
      const int ch = 2 * ni + (g >> 1);    // row q=r16, kv-chunk, half g&1
      *(bf16x4*)&pP[wave][r16 * 64 + ((ch ^ (r16 & 7)) * 8) + (g & 1) * 4] = pb;
    }
    rs += __shfl_xor(rs, 16);
    rs += __shfl_xor(rs, 32);
    lS[sd] += rs;
  };

  const int ntiles = 32 - i;         // KV tiles needed by side B (q-tile 31-i)
  ASTAGE(0, 0);
  asm volatile("s_waitcnt vmcnt(0)" ::: "memory");
  __syncthreads();
  int cur = 0;

  for (int t = 0; t < ntiles; ++t) {
    const int kv0 = t << 6;
    if (t + 1 < ntiles) ASTAGE(cur ^ 1, kv0 + 64);  // next tile under compute

    // ---- hoisted K/V fragment reads: once per tile, shared by both sides ----
    bf16x8 kf[2][4], vf[2][4];
    #pragma unroll
    for (int c = 0; c < 2; ++c)
      #pragma unroll
      for (int ni = 0; ni < 4; ++ni) {
        const int row = ni * 16 + r16;
        const int sw = ((c * 4 + g) ^ (row & 7)) * 8;
        kf[c][ni] = *(const bf16x8*)&lK[cur][row * 64 + sw];
        vf[c][ni] = *(const bf16x8*)&lV[cur][row * 64 + sw];
      }

    #pragma unroll
    for (int sd = 0; sd < 2; ++sd) {
      if (sd == 0 && t > i) continue;       // side A inactive past its diagonal
      const int qw = qtile[sd] * 64 + wave * 16;

      // ---- QK^T swapped: s[ni][j] = S[kv0+ni*16+g*4+j][qw+r16] ----
      f32x4 s[4] = {};
      #pragma unroll
      for (int c = 0; c < 2; ++c)
        #pragma unroll
        for (int ni = 0; ni < 4; ++ni)
          s[ni] = __builtin_amdgcn_mfma_f32_16x16x32_bf16(kf[c][ni], qf[sd][c], s[ni], 0, 0, 0);

      // ---- causal mask (diagonal tile of this side only) ----
      if (t == ((sd == 0) ? i : (ntiles - 1))) {
        #pragma unroll
        for (int ni = 0; ni < 4; ++ni)
          #pragma unroll
          for (int j = 0; j < 4; ++j)
            if (kv0 + ni * 16 + g * 4 + j > qw + r16) s[ni][j] = -__builtin_inff();
      }

      sm_side(s, sd);
      asm volatile("s_waitcnt lgkmcnt(0)" ::: "memory");  // P writes drained

      // ---- PV: O += P * V^T, 8 MFMAs (vf from registers) ----
      #pragma unroll
      for (int c = 0; c < 2; ++c) {
        const bf16x8 pf = *(const bf16x8*)&pP[wave][r16 * 64 + (((c * 4 + g) ^ (r16 & 7)) * 8)];
        #pragma unroll
        for (int nf = 0; nf < 4; ++nf)
          o[sd][nf] = __builtin_amdgcn_mfma_f32_16x16x32_bf16(pf, vf[c][nf], o[sd][nf], 0, 0, 0);
      }
    }

    asm volatile("s_waitcnt vmcnt(0)" ::: "memory");  // next-tile loads landed
    __syncthreads();
    cur ^= 1;
  }

  // ---- epilogue -> Y[b][t][h][d] bf16 (both sides); l via shfl ----
  #pragma unroll
  for (int sd = 0; sd < 2; ++sd) {
    const int qw = qtile[sd] * 64 + wave * 16;
    #pragma unroll
    for (int j = 0; j < 4; ++j) {
      const float lq = __shfl(lS[sd], g * 4 + j);
      const float inv = 1.0f / lq;
      const int tq = qw + g * 4 + j;
      #pragma unroll
      for (int nf = 0; nf < 4; ++nf) {
        const int d = nf * 16 + r16;
        Y[(((size_t)b * T_ + tq) * NH_ + h) * HD_ + d] = (__bf16)(o[sd][nf][j] * inv);
      }
    }
  }
#undef ASTAGE
}

extern "C" void kernel_launch(void* const* d_in, const int* in_sizes, int n_in,
                              void* d_out, int out_size, void* d_ws, size_t ws_size,
                              hipStream_t stream) {
  const float* x = (const float*)d_in[0];
  const float* Wqkv = (const float*)d_in[1];
  const float* Wproj = (const float*)d_in[2];
  float* out = (float*)d_out;

  char* ws = (char*)d_ws;
  size_t off = 0;
  auto alloc = [&](size_t bytes) {
    char* p = ws + off;
    off += (bytes + 255) & ~(size_t)255;
    return p;
  };
  __bf16* xb     = (__bf16*)alloc((size_t)M_ * C_ * 2);          // 8 MB
  __bf16* wqkvT  = (__bf16*)alloc((size_t)NQKV_ * C_ * 2);       // 3 MB
  __bf16* wprojT = (__bf16*)alloc((size_t)C_ * C_ * 2);          // 2 MB
  float*  cosT   = (float*)alloc((size_t)T_ * 32 * 4);
  float*  sinT   = (float*)alloc((size_t)T_ * 32 * 4);
  __bf16* qkv    = (__bf16*)alloc((size_t)M_ * NQKV_ * 2);       // 12.6 MB (bf16)
  __bf16* Qb     = (__bf16*)alloc((size_t)B_ * NH_ * T_ * HD_ * 2);
  __bf16* Kb     = (__bf16*)alloc((size_t)B_ * NKV_ * T_ * HD_ * 2);
  __bf16* Vt     = (__bf16*)alloc((size_t)B_ * NKV_ * T_ * HD_ * 2);
  __bf16* Yb     = (__bf16*)alloc((size_t)M_ * C_ * 2);          // 8 MB

  hipLaunchKernelGGL(cast_x_kernel, dim3(M_ * C_ / 4 / 256), dim3(256), 0, stream, x, xb);
  hipLaunchKernelGGL(transpose_cast_kernel, dim3(NQKV_ / 64, C_ / 64), dim3(256), 0, stream,
                     Wqkv, wqkvT, C_, NQKV_);
  hipLaunchKernelGGL(transpose_cast_kernel, dim3(C_ / 64, C_ / 64), dim3(256), 0, stream,
                     Wproj, wprojT, C_, C_);
  hipLaunchKernelGGL(rope_table_kernel, dim3(T_ * 32 / 256), dim3(256), 0, stream, cosT, sinT);
  hipLaunchKernelGGL(HIP_KERNEL_NAME(gemm_tn_kernel<__bf16>), dim3(NQKV_ / 64, M_ / 128),
                     dim3(256), 0, stream, xb, wqkvT, qkv, NQKV_, C_);
  hipLaunchKernelGGL(rope_qk_kernel, dim3(M_ * (NH_ + NKV_) * 8 / 256), dim3(256), 0, stream,
                     qkv, cosT, sinT, Qb, Kb);
  hipLaunchKernelGGL(v_transpose_kernel, dim3(B_ * NKV_ * (T_ / 64)), dim3(256), 0, stream,
                     qkv, Vt);
  hipLaunchKernelGGL(attn_kernel, dim3(16 * B_ * NH_), dim3(256), 0, stream, Qb, Kb, Vt, Yb);
  hipLaunchKernelGGL(HIP_KERNEL_NAME(gemm_tn_kernel<float>), dim3(C_ / 64, M_ / 128),
                     dim3(256), 0, stream, Yb, wprojT, out, C_, C_);
}

// Round 12
// 98.025 us; speedup vs baseline: 1.0790x; 1.0790x over previous
//
#include <hip/hip_runtime.h>
#include <hip/hip_bf16.h>

#define B_ 2
#define T_ 2048
#define C_ 1024
#define NH_ 16
#define NKV_ 4
#define HD_ 64
#define NQKV_ 1536           // (NH + 2*NKV) * HD
#define M_ 4096              // B_ * T_

typedef __attribute__((ext_vector_type(8))) __bf16 bf16x8;
typedef __attribute__((ext_vector_type(4))) __bf16 bf16x4;
typedef __attribute__((ext_vector_type(2))) __bf16 bf16x2;
typedef __attribute__((ext_vector_type(4))) float f32x4;
typedef __attribute__((ext_vector_type(4))) unsigned int u32x4;

// raw v_exp_f32 (D = 2^S0): 1 instruction, ~1 ulp — plenty for bf16 outputs.
__device__ __forceinline__ float fast_exp2(float x) { return __builtin_amdgcn_exp2f(x); }

#define GLOAD_LDS16(gptr, lptr)                                                        \
  __builtin_amdgcn_global_load_lds(                                                    \
      (const __attribute__((address_space(1))) unsigned int*)(gptr),                   \
      (__attribute__((address_space(3))) unsigned int*)(lptr), 16, 0, 0)

// ---- shared transpose-tile body: in [K][N] fp32 -> out [N][K] bf16 ----
__device__ __forceinline__ void transpose_tile_body(const float* __restrict__ in,
                                                    __bf16* __restrict__ out,
                                                    int K, int N, int n0, int k0,
                                                    __bf16 (*tile)[72], int tid) {
  const int tr = tid >> 4, tc4 = (tid & 15) << 2;
  #pragma unroll
  for (int p = 0; p < 4; ++p) {
    const int k = k0 + p * 16 + tr;
    const float4 v = *(const float4*)&in[(size_t)k * N + n0 + tc4];
    tile[tc4 + 0][p * 16 + tr] = (__bf16)v.x;
    tile[tc4 + 1][p * 16 + tr] = (__bf16)v.y;
    tile[tc4 + 2][p * 16 + tr] = (__bf16)v.z;
    tile[tc4 + 3][p * 16 + tr] = (__bf16)v.w;
  }
  __syncthreads();
  #pragma unroll
  for (int p = 0; p < 4; ++p) {
    const int n = n0 + p * 16 + tr;
    bf16x4 o;
    o.x = tile[p * 16 + tr][tc4 + 0];
    o.y = tile[p * 16 + tr][tc4 + 1];
    o.z = tile[p * 16 + tr][tc4 + 2];
    o.w = tile[p * 16 + tr][tc4 + 3];
    *(bf16x4*)&out[(size_t)n * K + k0 + tc4] = o;
  }
}

// ---- fused prep: cast_x (2048 blk) | T(Wqkv) (384) | T(Wproj) (256) |
//      rope_table (256). Independent stages share one launch so they fill
//      the machine concurrently (stream-capture graphs serialize launches).
#define NB_CASTX 2048
#define NB_TWQKV 384
#define NB_TWPROJ 256
#define PREP_GRID (NB_CASTX + NB_TWQKV + NB_TWPROJ + 256)
__global__ __launch_bounds__(256) void prep_kernel(const float* __restrict__ x,
                                                   const float* __restrict__ Wqkv,
                                                   const float* __restrict__ Wproj,
                                                   __bf16* __restrict__ xb,
                                                   __bf16* __restrict__ wqkvT,
                                                   __bf16* __restrict__ wprojT,
                                                   float* __restrict__ cosT,
                                                   float* __restrict__ sinT) {
  __shared__ __bf16 tile[64][72];
  const int blk = blockIdx.x, tid = threadIdx.x;
  if (blk < NB_CASTX) {                      // cast x: 8 elems/thread
    const int i = blk * 256 + tid;
    const float4 v0 = ((const float4*)x)[2 * i];
    const float4 v1 = ((const float4*)x)[2 * i + 1];
    bf16x8 o;
    o[0] = (__bf16)v0.x; o[1] = (__bf16)v0.y; o[2] = (__bf16)v0.z; o[3] = (__bf16)v0.w;
    o[4] = (__bf16)v1.x; o[5] = (__bf16)v1.y; o[6] = (__bf16)v1.z; o[7] = (__bf16)v1.w;
    ((bf16x8*)xb)[i] = o;
  } else if (blk < NB_CASTX + NB_TWQKV) {    // transpose Wqkv [C][NQKV]->[NQKV][C]
    const int bx = blk - NB_CASTX;
    transpose_tile_body(Wqkv, wqkvT, C_, NQKV_, (bx % (NQKV_ / 64)) * 64,
                        (bx / (NQKV_ / 64)) * 64, tile, tid);
  } else if (blk < NB_CASTX + NB_TWQKV + NB_TWPROJ) {  // transpose Wproj
    const int bx = blk - NB_CASTX - NB_TWQKV;
    transpose_tile_body(Wproj, wprojT, C_, C_, (bx % (C_ / 64)) * 64,
                        (bx / (C_ / 64)) * 64, tile, tid);
  } else {                                   // RoPE cos/sin tables [T][32]
    const int idx = (blk - NB_CASTX - NB_TWQKV - NB_TWPROJ) * 256 + tid;
    const int t = idx >> 5, i = idx & 31;
    const float inv = powf(10000.0f, -(float)i * (1.0f / 32.0f));
    const float ang = (float)t * inv;
    cosT[idx] = cosf(ang);
    sinT[idx] = sinf(ang);
  }
}

// ------- bf16 TN GEMM: A[M][K] * Bt[N][K]^T -> C[M][N] (OutT) -------
// 128x64 tile, BK=64, 4 waves (2x2, each 64x32 out). Double-buffered
// global_load_lds (w=16): stage(t+1) issues BEFORE compute(t); vmcnt(0)+
// barrier once per tile. Pre-swizzled SOURCE + linear LDS dest (rule 21).
template <typename OutT>
__global__ __launch_bounds__(256) void gemm_tn_kernel(const __bf16* __restrict__ A,
                                                      const __bf16* __restrict__ Bt,
                                                      OutT* __restrict__ C, int N, int K) {
  __shared__ __align__(16) __bf16 lA[2][128 * 64];
  __shared__ __align__(16) __bf16 lB[2][64 * 64];
  const int tid = threadIdx.x;
  const int lane = tid & 63;
  const int wave = tid >> 6;
  const int wr = wave >> 1, wc = wave & 1;
  const int m0 = blockIdx.y * 128, n0 = blockIdx.x * 64;
  const int srow = tid >> 3, kc = tid & 7;  // staging: 8 threads/row, 16B chunks
  const int r16 = lane & 15, g = lane >> 4;
  f32x4 acc[4][2] = {};
  const int nt = K >> 6;

#define GSTAGE(buf, k0)                                                                   \
  {                                                                                       \
    _Pragma("unroll")                                                                     \
    for (int p = 0; p < 4; ++p) {                                                         \
      const int row = p * 32 + srow;                                                      \
      const int sw = (kc ^ (row & 7)) * 8;                                                \
      GLOAD_LDS16(&A[(size_t)(m0 + row) * K + (k0) + sw], &lA[buf][row * 64 + kc * 8]);   \
    }                                                                                     \
    _Pragma("unroll")                                                                     \
    for (int p = 0; p < 2; ++p) {                                                         \
      const int row = p * 32 + srow;                                                      \
      const int sw = (kc ^ (row & 7)) * 8;                                                \
      GLOAD_LDS16(&Bt[(size_t)(n0 + row) * K + (k0) + sw], &lB[buf][row * 64 + kc * 8]);  \
    }                                                                                     \
  }

  GSTAGE(0, 0);
  asm volatile("s_waitcnt vmcnt(0)" ::: "memory");
  __syncthreads();
  int cur = 0;
  for (int t = 0; t < nt; ++t) {
    if (t + 1 < nt) GSTAGE(cur ^ 1, (t + 1) << 6);   // loads fly under compute
    #pragma unroll
    for (int ks = 0; ks < 64; ks += 32) {
      bf16x8 af[4], bfr[2];
      const int kch = (ks >> 3) + g;
      #pragma unroll
      for (int mi = 0; mi < 4; ++mi) {
        const int row = wr * 64 + mi * 16 + r16;
        af[mi] = *(const bf16x8*)&lA[cur][row * 64 + (kch ^ (row & 7)) * 8];
      }
      #pragma unroll
      for (int ni = 0; ni < 2; ++ni) {
        const int row = wc * 32 + ni * 16 + r16;
        bfr[ni] = *(const bf16x8*)&lB[cur][row * 64 + (kch ^ (row & 7)) * 8];
      }
      #pragma unroll
      for (int mi = 0; mi < 4; ++mi)
        #pragma unroll
        for (int ni = 0; ni < 2; ++ni)
          acc[mi][ni] = __builtin_amdgcn_mfma_f32_16x16x32_bf16(af[mi], bfr[ni], acc[mi][ni], 0, 0, 0);
    }
    asm volatile("s_waitcnt vmcnt(0)" ::: "memory");  // next-tile loads landed
    __syncthreads();
    cur ^= 1;
  }
  // epilogue: D layout col=lane&15, row=(lane>>4)*4+j
  #pragma unroll
  for (int mi = 0; mi < 4; ++mi) {
    const int r0 = m0 + wr * 64 + mi * 16 + g * 4;
    #pragma unroll
    for (int ni = 0; ni < 2; ++ni) {
      const int c = n0 + wc * 32 + ni * 16 + r16;
      #pragma unroll
      for (int j = 0; j < 4; ++j)
        C[(size_t)(r0 + j) * N + c] = (OutT)acc[mi][ni][j];
    }
  }
#undef GSTAGE
}

// ---- fused post: rope_qk (2560 blk) | v_transpose (256 blk) ----
#define NB_ROPEQK 2560
#define POST_GRID (NB_ROPEQK + 256)
__global__ __launch_bounds__(256) void post_kernel(const __bf16* __restrict__ qkv,
                                                   const float* __restrict__ cosT,
                                                   const float* __restrict__ sinT,
                                                   __bf16* __restrict__ Q,
                                                   __bf16* __restrict__ Kb,
                                                   __bf16* __restrict__ Vt) {
  __shared__ __bf16 tile[64][72];
  const int tid = threadIdx.x;
  if (blockIdx.x < NB_ROPEQK) {
    // RoPE q,k: 8 elems (4 pairs)/thread; Q pre-scaled by 1/8*log2(e).
    const int idx = blockIdx.x * 256 + tid;
    const int i8 = idx & 7;
    const int rest = idx >> 3;
    const int head = rest % (NH_ + NKV_);
    const int row = rest / (NH_ + NKV_);
    const int b = row >> 11, t = row & 2047;
    const float4 cv = *(const float4*)&cosT[t * 32 + i8 * 4];
    const float4 sv = *(const float4*)&sinT[t * 32 + i8 * 4];
    const bf16x8 v = *(const bf16x8*)&qkv[(size_t)row * NQKV_ + head * HD_ + i8 * 8];
    const bool isq = head < NH_;
    const float qs = isq ? 0.125f * 1.44269504f : 1.0f;
    bf16x8 o;
    #pragma unroll
    for (int p = 0; p < 4; ++p) {
      const float x1 = (float)v[2 * p], x2 = (float)v[2 * p + 1];
      const float c = (&cv.x)[p], s = (&sv.x)[p];
      o[2 * p]     = (__bf16)((x1 * c - x2 * s) * qs);
      o[2 * p + 1] = (__bf16)((x1 * s + x2 * c) * qs);
    }
    __bf16* dst = isq ? &Q[(((size_t)b * NH_ + head) * T_ + t) * HD_ + i8 * 8]
                      : &Kb[(((size_t)b * NKV_ + (head - NH_)) * T_ + t) * HD_ + i8 * 8];
    *(bf16x8*)dst = o;
  } else {
    // V transpose -> Vt[b][kvh][d][t]
    const int blk = blockIdx.x - NB_ROPEQK;  // B*NKV*(T/64)
    const int t0 = (blk & 31) * 64;
    const int kvh = (blk >> 5) & 3;
    const int b = blk >> 7;
    const int tr = tid >> 4, c4 = (tid & 15) << 2;
    #pragma unroll
    for (int p = 0; p < 4; ++p) {
      const int t = t0 + p * 16 + tr;
      const bf16x4 v = *(const bf16x4*)&qkv[(size_t)(b * T_ + t) * NQKV_ + (NH_ + NKV_) * HD_ + kvh * HD_ + c4];
      tile[c4 + 0][p * 16 + tr] = v.x;
      tile[c4 + 1][p * 16 + tr] = v.y;
      tile[c4 + 2][p * 16 + tr] = v.z;
      tile[c4 + 3][p * 16 + tr] = v.w;
    }
    __syncthreads();
    #pragma unroll
    for (int p = 0; p < 4; ++p) {
      const int d = p * 16 + tr;
      bf16x4 o;
      o.x = tile[d][c4 + 0]; o.y = tile[d][c4 + 1];
      o.z = tile[d][c4 + 2]; o.w = tile[d][c4 + 3];
      *(bf16x4*)&Vt[(((size_t)b * NKV_ + kvh) * HD_ + d) * T_ + t0 + c4] = o;
    }
  }
}

// ---- flash attention, triangle-paired, swapped-QK softmax, K/V LDS dbuf ----
// Block pair index i handles q-tiles {i, 31-i} in one shared KV sweep (33
// tile-activations/block -> uniform). K/V double-buffered in LDS via
// global_load_lds; ONE barrier per tile; kf/vf hoisted per tile, shared by
// both active sides. Per-side: QK -> softmax (in-lane, fast_exp2) -> PV.
__global__ __launch_bounds__(256) void attn_kernel(const __bf16* __restrict__ Q,
                                                   const __bf16* __restrict__ Kb,
                                                   const __bf16* __restrict__ Vt,
                                                   __bf16* __restrict__ Y) {
  __shared__ __align__(16) __bf16 lK[2][64 * 64];   // [kv][d], swizzled
  __shared__ __align__(16) __bf16 lV[2][64 * 64];   // [d][kv], swizzled
  __shared__ __align__(16) __bf16 pP[4][16 * 64];   // per-wave [q][kv], swizzled
  const int tid = threadIdx.x;
  const int lane = tid & 63, wave = tid >> 6;
  const int r16 = lane & 15, g = lane >> 4;
  // bijective XCD swizzle (T1): 512 blocks, 8 XCDs -> 64 contiguous logical
  // ids per XCD so blocks sharing (b,kvh)'s K/V co-locate in one L2.
  const int logical = (blockIdx.x & 7) * 64 + (blockIdx.x >> 3);
  const int i = logical & 15;        // pair index: q-tiles {i, 31-i}
  const int bh = logical >> 4;
  const int b = bh >> 4, h = bh & 15;
  const int kvh = h >> 2;  // GQA rep = 4
  const __bf16* Qp = Q + ((size_t)b * NH_ + h) * T_ * HD_;
  const __bf16* Kp = Kb + ((size_t)b * NKV_ + kvh) * T_ * HD_;
  const __bf16* Vp = Vt + ((size_t)b * NKV_ + kvh) * HD_ * T_;
  const int qtile[2] = { i, 31 - i };
  const int srow = tid >> 3, kc = tid & 7;          // staging: 8x16B chunks/row

#define ASTAGE(buf, kv0_)                                                                  \
  {                                                                                        \
    _Pragma("unroll")                                                                      \
    for (int p = 0; p < 2; ++p) {                                                          \
      const int row = p * 32 + srow;                                                       \
      const int sw = (kc ^ (row & 7)) * 8;                                                 \
      GLOAD_LDS16(&Kp[(size_t)((kv0_) + row) * HD_ + sw], &lK[buf][row * 64 + kc * 8]);    \
      GLOAD_LDS16(&Vp[(size_t)row * T_ + (kv0_) + sw], &lV[buf][row * 64 + kc * 8]);       \
    }                                                                                      \
  }

  // Q fragments; pre-scaled by 1/8*log2e in rope path. B-operand of swapped QK.
  bf16x8 qf[2][2];
  #pragma unroll
  for (int sd = 0; sd < 2; ++sd)
    #pragma unroll
    for (int c = 0; c < 2; ++c)
      qf[sd][c] = *(const bf16x8*)&Qp[(size_t)(qtile[sd] * 64 + wave * 16 + r16) * HD_ + (c * 4 + g) * 8];

  f32x4 o[2][4] = {};
  float mS[2], lS[2];
  #pragma unroll
  for (int sd = 0; sd < 2; ++sd) { mS[sd] = -__builtin_inff(); lS[sd] = 0.0f; }

  // softmax + P-write for one side (lane owns full row q=qw+r16 of S^T)
  auto sm_side = [&](f32x4 (&s)[4], int sd) {
    // in-lane 16->1 max, max3-shaped triples (T17)
    float t0 = fmaxf(fmaxf(s[0][0], s[0][1]), s[0][2]);
    float t1 = fmaxf(fmaxf(s[0][3], s[1][0]), s[1][1]);
    float t2 = fmaxf(fmaxf(s[1][2], s[1][3]), s[2][0]);
    float t3 = fmaxf(fmaxf(s[2][1], s[2][2]), s[2][3]);
    float t4 = fmaxf(fmaxf(s[3][0], s[3][1]), s[3][2]);
    float pm = fmaxf(fmaxf(t0, t1), t2);
    pm = fmaxf(pm, fmaxf(t3, t4));
    pm = fmaxf(pm, s[3][3]);
    pm = fmaxf(pm, __shfl_xor(pm, 16));
    pm = fmaxf(pm, __shfl_xor(pm, 32));
    const bool upd = pm > mS[sd] + 8.0f;   // deferred-max (T13)
    const float nm = upd ? pm : mS[sd];
    const float sc = fast_exp2(mS[sd] - nm);   // ==1.0 exactly when !upd
    mS[sd] = nm;
    lS[sd] *= sc;
    if (__any(upd)) {  // redistribute sc from q=r16 layout to (g,j) layout
      #pragma unroll
      for (int j = 0; j < 4; ++j) {
        const float scj = __shfl(sc, g * 4 + j);
        #pragma unroll
        for (int nf = 0; nf < 4; ++nf) o[sd][nf][j] *= scj;
      }
    }
    // P = exp2(S-m): write each pb chunk ASAP, reduce rs after.
    float rs = 0.0f;
    #pragma unroll
    for (int ni = 0; ni < 4; ++ni) {
      bf16x4 pb;
      #pragma unroll
      for (int j = 0; j < 4; ++j) {
        const float pv = fast_exp2(s[ni][j] - mS[sd]);
        rs += pv;
        pb[j] = (__bf16)pv;
      }
      const int ch = 2 * ni + (g >> 1);    // row q=r16, kv-chunk, half g&1
      *(bf16x4*)&pP[wave][r16 * 64 + ((ch ^ (r16 & 7)) * 8) + (g & 1) * 4] = pb;
    }
    rs += __shfl_xor(rs, 16);
    rs += __shfl_xor(rs, 32);
    lS[sd] += rs;
  };

  const int ntiles = 32 - i;         // KV tiles needed by side B (q-tile 31-i)
  ASTAGE(0, 0);
  asm volatile("s_waitcnt vmcnt(0)" ::: "memory");
  __syncthreads();
  int cur = 0;

  for (int t = 0; t < ntiles; ++t) {
    const int kv0 = t << 6;
    if (t + 1 < ntiles) ASTAGE(cur ^ 1, kv0 + 64);  // next tile under compute

    // ---- hoisted K/V fragment reads: once per tile, shared by both sides ----
    bf16x8 kf[2][4], vf[2][4];
    #pragma unroll
    for (int c = 0; c < 2; ++c)
      #pragma unroll
      for (int ni = 0; ni < 4; ++ni) {
        const int row = ni * 16 + r16;
        const int sw = ((c * 4 + g) ^ (row & 7)) * 8;
        kf[c][ni] = *(const bf16x8*)&lK[cur][row * 64 + sw];
        vf[c][ni] = *(const bf16x8*)&lV[cur][row * 64 + sw];
      }

    #pragma unroll
    for (int sd = 0; sd < 2; ++sd) {
      if (sd == 0 && t > i) continue;       // side A inactive past its diagonal
      const int qw = qtile[sd] * 64 + wave * 16;

      // ---- QK^T swapped: s[ni][j] = S[kv0+ni*16+g*4+j][qw+r16] ----
      f32x4 s[4] = {};
      #pragma unroll
      for (int c = 0; c < 2; ++c)
        #pragma unroll
        for (int ni = 0; ni < 4; ++ni)
          s[ni] = __builtin_amdgcn_mfma_f32_16x16x32_bf16(kf[c][ni], qf[sd][c], s[ni], 0, 0, 0);

      // ---- causal mask (diagonal tile of this side only) ----
      if (t == ((sd == 0) ? i : (ntiles - 1))) {
        #pragma unroll
        for (int ni = 0; ni < 4; ++ni)
          #pragma unroll
          for (int j = 0; j < 4; ++j)
            if (kv0 + ni * 16 + g * 4 + j > qw + r16) s[ni][j] = -__builtin_inff();
      }

      sm_side(s, sd);
      asm volatile("s_waitcnt lgkmcnt(0)" ::: "memory");  // P writes drained

      // ---- PV: O += P * V^T, 8 MFMAs (vf from registers) ----
      #pragma unroll
      for (int c = 0; c < 2; ++c) {
        const bf16x8 pf = *(const bf16x8*)&pP[wave][r16 * 64 + (((c * 4 + g) ^ (r16 & 7)) * 8)];
        #pragma unroll
        for (int nf = 0; nf < 4; ++nf)
          o[sd][nf] = __builtin_amdgcn_mfma_f32_16x16x32_bf16(pf, vf[c][nf], o[sd][nf], 0, 0, 0);
      }
    }

    asm volatile("s_waitcnt vmcnt(0)" ::: "memory");  // next-tile loads landed
    __syncthreads();
    cur ^= 1;
  }

  // ---- epilogue -> Y[b][t][h][d] bf16 (both sides); l via shfl ----
  #pragma unroll
  for (int sd = 0; sd < 2; ++sd) {
    const int qw = qtile[sd] * 64 + wave * 16;
    #pragma unroll
    for (int j = 0; j < 4; ++j) {
      const float lq = __shfl(lS[sd], g * 4 + j);
      const float inv = 1.0f / lq;
      const int tq = qw + g * 4 + j;
      #pragma unroll
      for (int nf = 0; nf < 4; ++nf) {
        const int d = nf * 16 + r16;
        Y[(((size_t)b * T_ + tq) * NH_ + h) * HD_ + d] = (__bf16)(o[sd][nf][j] * inv);
      }
    }
  }
#undef ASTAGE
}

extern "C" void kernel_launch(void* const* d_in, const int* in_sizes, int n_in,
                              void* d_out, int out_size, void* d_ws, size_t ws_size,
                              hipStream_t stream) {
  const float* x = (const float*)d_in[0];
  const float* Wqkv = (const float*)d_in[1];
  const float* Wproj = (const float*)d_in[2];
  float* out = (float*)d_out;

  char* ws = (char*)d_ws;
  size_t off = 0;
  auto alloc = [&](size_t bytes) {
    char* p = ws + off;
    off += (bytes + 255) & ~(size_t)255;
    return p;
  };
  __bf16* xb     = (__bf16*)alloc((size_t)M_ * C_ * 2);          // 8 MB
  __bf16* wqkvT  = (__bf16*)alloc((size_t)NQKV_ * C_ * 2);       // 3 MB
  __bf16* wprojT = (__bf16*)alloc((size_t)C_ * C_ * 2);          // 2 MB
  float*  cosT   = (float*)alloc((size_t)T_ * 32 * 4);
  float*  sinT   = (float*)alloc((size_t)T_ * 32 * 4);
  __bf16* qkv    = (__bf16*)alloc((size_t)M_ * NQKV_ * 2);       // 12.6 MB (bf16)
  __bf16* Qb     = (__bf16*)alloc((size_t)B_ * NH_ * T_ * HD_ * 2);
  __bf16* Kb     = (__bf16*)alloc((size_t)B_ * NKV_ * T_ * HD_ * 2);
  __bf16* Vt     = (__bf16*)alloc((size_t)B_ * NKV_ * T_ * HD_ * 2);
  __bf16* Yb     = (__bf16*)alloc((size_t)M_ * C_ * 2);          // 8 MB

  hipLaunchKernelGGL(prep_kernel, dim3(PREP_GRID), dim3(256), 0, stream,
                     x, Wqkv, Wproj, xb, wqkvT, wprojT, cosT, sinT);
  hipLaunchKernelGGL(HIP_KERNEL_NAME(gemm_tn_kernel<__bf16>), dim3(NQKV_ / 64, M_ / 128),
                     dim3(256), 0, stream, xb, wqkvT, qkv, NQKV_, C_);
  hipLaunchKernelGGL(post_kernel, dim3(POST_GRID), dim3(256), 0, stream,
                     qkv, cosT, sinT, Qb, Kb, Vt);
  hipLaunchKernelGGL(attn_kernel, dim3(16 * B_ * NH_), dim3(256), 0, stream, Qb, Kb, Vt, Yb);
  hipLaunchKernelGGL(HIP_KERNEL_NAME(gemm_tn_kernel<float>), dim3(C_ / 64, M_ / 128),
                     dim3(256), 0, stream, Yb, wprojT, out, C_, C_);
}